// Round 3
// baseline (292.106 us; speedup 1.0000x reference)
//
#include <hip/hip_runtime.h>
#include <math.h>

// src [B=16,S=4096,DM=768] fp32, mask [B,S] bool, query [H=8,D=96] fp32,
// out [B,768] fp32.
//   w_s = exp(q.k_s)  (scores ~ N(0,1): no max-subtraction needed in fp32)
//   out = (sum_s w_s k_s + sum_s w_s pe_s) / sum_s w_s
// Pass 1 streams src once (the only big read): w, sum w, sum w*k.
// Pass 2 computes sum_s w_s * pe[s,c] from the 2 MB w array (L2-hot) with a
// sin/cos rotation recurrence. Pass 3 merges partials and divides.
namespace {
constexpr int kB = 16;
constexpr int kS = 4096;
constexpr int kH = 8;
constexpr int kD = 96;
constexpr int kDM = 768;
constexpr int kNChunk = 16;            // pass-1 s-chunks: 16*8*16 = 2048 blocks
constexpr int kCS = kS / kNChunk;      // 256 rows per chunk
constexpr int kRPI = 32;               // row slots in flight (r = t>>3)
constexpr int kIters = kCS / kRPI;     // 8
constexpr int kNSC2 = 32;              // pass-2 s-chunks (128 s each)
constexpr int kS2 = kS / kNSC2;        // 128
constexpr float kPeScale = 0.03608439182435161f;        // 768^-0.5
constexpr float kNegLog = -9.210340371976184f / 768.0f; // -ln(1e4)/768
constexpr float kHalfPi = 1.5707963267948966f;
}

// One block per (b,h,chunk). 256 threads: j = t&7 -> 3 float4 of the 96-dim
// head slice; r = t>>3 -> row slot. Register-light (~50 VGPR) so 8 waves/SIMD.
__global__ __launch_bounds__(256, 8)
void attn_pass1_kernel(const float* __restrict__ src,
                       const unsigned char* __restrict__ mask,
                       const float* __restrict__ query,
                       float* __restrict__ wsO,
                       float* __restrict__ wsL,
                       float* __restrict__ wsW)
{
    const int blk = blockIdx.x;
    const int chunk = blk & (kNChunk - 1);
    const int bh = blk >> 4;
    const int b = bh >> 3;
    const int h = bh & 7;
    const int t = (int)threadIdx.x;
    const int j = t & 7;
    const int r = t >> 3;
    const int lane = t & 63;
    const int wave = t >> 6;

    const float* qh = query + h * kD + 4 * j;
    const float4 q0 = *(const float4*)(qh);
    const float4 q1 = *(const float4*)(qh + 32);
    const float4 q2 = *(const float4*)(qh + 64);

    float l = 0.0f;
    float o[12];
#pragma unroll
    for (int k = 0; k < 12; ++k) o[k] = 0.0f;

    const int s0 = chunk * kCS + r;
    const float* baseT = src + ((size_t)b * kS + s0) * kDM + h * kD + 4 * j;
    const unsigned char* mbase = mask + (size_t)b * kS + s0;
    float* wbase = wsW + (size_t)bh * kS + s0;

#pragma unroll 1
    for (int it = 0; it < kIters; ++it) {
        const float* rp = baseT + (size_t)(it * kRPI) * kDM;
        const float4 x0 = *(const float4*)(rp);
        const float4 x1 = *(const float4*)(rp + 32);
        const float4 x2 = *(const float4*)(rp + 64);
        const unsigned char mk = mbase[it * kRPI];

        float pd = x0.x * q0.x + x0.y * q0.y + x0.z * q0.z + x0.w * q0.w
                 + x1.x * q1.x + x1.y * q1.y + x1.z * q1.z + x1.w * q1.w
                 + x2.x * q2.x + x2.y * q2.y + x2.z * q2.z + x2.w * q2.w;
        pd += __shfl_xor(pd, 1, 8);
        pd += __shfl_xor(pd, 2, 8);
        pd += __shfl_xor(pd, 4, 8);

        const float w = mk ? 0.0f : __expf(pd);
        l += w;

        o[0]  = fmaf(w, x0.x, o[0]);
        o[1]  = fmaf(w, x0.y, o[1]);
        o[2]  = fmaf(w, x0.z, o[2]);
        o[3]  = fmaf(w, x0.w, o[3]);
        o[4]  = fmaf(w, x1.x, o[4]);
        o[5]  = fmaf(w, x1.y, o[5]);
        o[6]  = fmaf(w, x1.z, o[6]);
        o[7]  = fmaf(w, x1.w, o[7]);
        o[8]  = fmaf(w, x2.x, o[8]);
        o[9]  = fmaf(w, x2.y, o[9]);
        o[10] = fmaf(w, x2.z, o[10]);
        o[11] = fmaf(w, x2.w, o[11]);

        if (j == 0) wbase[it * kRPI] = w;   // one store per row
    }

    // ---- block-level merge ----
    __shared__ float ssum[4];
    __shared__ float osh[4][8][12];

    float lv = (j == 0) ? l : 0.0f;
#pragma unroll
    for (int msk = 32; msk >= 1; msk >>= 1) lv += __shfl_xor(lv, msk, 64);
    if (lane == 0) ssum[wave] = lv;

#pragma unroll
    for (int k = 0; k < 12; ++k) {
        float v = o[k];
        v += __shfl_xor(v, 8, 64);
        v += __shfl_xor(v, 16, 64);
        v += __shfl_xor(v, 32, 64);
        o[k] = v;
    }
    if (lane < 8) {
#pragma unroll
        for (int k = 0; k < 12; ++k) osh[wave][lane][k] = o[k];
    }
    __syncthreads();

    const int pidx = bh * kNChunk + chunk;
    if (t < kD) {
        const int kk = t >> 5;
        const int jj = (t & 31) >> 2;
        const int qq = t & 3;
        const int idx = kk * 4 + qq;
        wsO[(size_t)pidx * kD + t] = osh[0][jj][idx] + osh[1][jj][idx]
                                   + osh[2][jj][idx] + osh[3][jj][idx];
    }
    if (t == 0) {
        wsL[pidx] = ssum[0] + ssum[1] + ssum[2] + ssum[3];
    }
}

// Pass 2: wsP[(bh*32+sc)*96 + c] = kPeScale * sum_{s in chunk} w[bh][s] *
//   sin(s*f_c + (c odd ? pi/2 : 0)),  f_c = exp(-ln(1e4)*(h*96 + (c&~1))/768).
// Rotation recurrence: 1 load + 5 FMA-class ops per s. w is L2-hot.
__global__ __launch_bounds__(128)
void attn_pe_kernel(const float* __restrict__ wsW, float* __restrict__ wsP)
{
    const int blk = (int)blockIdx.x;       // bh*32 + sc
    const int sc = blk & (kNSC2 - 1);
    const int bh = blk >> 5;
    const int h = bh & 7;
    const int c = (int)threadIdx.x;
    if (c >= kD) return;

    const float f = __expf(kNegLog * (float)(h * kD + (c & ~1)));
    const int s0 = sc * kS2;
    float sn, cs;
    __sincosf((float)s0 * f + ((c & 1) ? kHalfPi : 0.0f), &sn, &cs);
    float ds, dc;
    __sincosf(f, &ds, &dc);

    const float* wp = wsW + (size_t)bh * kS + s0;
    float acc = 0.0f;
#pragma unroll 4
    for (int i = 0; i < kS2; ++i) {
        const float w = wp[i];
        acc = fmaf(w, sn, acc);
        const float ns = fmaf(sn, dc, cs * ds);
        const float nc = fmaf(cs, dc, -sn * ds);
        sn = ns; cs = nc;
    }
    wsP[(size_t)blk * kD + c] = acc * kPeScale;
}

// Pass 3: out[bh*96+c] = (sum_16 O + sum_32 P) / sum_16 L.
__global__ __launch_bounds__(128)
void attn_combine_kernel(const float* __restrict__ wsO,
                         const float* __restrict__ wsL,
                         const float* __restrict__ wsP,
                         float* __restrict__ out)
{
    const int bh = (int)blockIdx.x;
    const int t = (int)threadIdx.x;

    float L = 0.0f;
#pragma unroll
    for (int k = 0; k < kNChunk; ++k) L += wsL[bh * kNChunk + k];

    if (t < kD) {
        float acc = 0.0f;
#pragma unroll
        for (int k = 0; k < kNChunk; ++k)
            acc += wsO[(size_t)(bh * kNChunk + k) * kD + t];
#pragma unroll
        for (int k = 0; k < kNSC2; ++k)
            acc += wsP[(size_t)(bh * kNSC2 + k) * kD + t];
        out[(size_t)bh * kD + t] = acc / L;
    }
}

extern "C" void kernel_launch(void* const* d_in, const int* in_sizes, int n_in,
                              void* d_out, int out_size, void* d_ws, size_t ws_size,
                              hipStream_t stream)
{
    const float* src = (const float*)d_in[0];
    const unsigned char* mask = (const unsigned char*)d_in[1];
    const float* query = (const float*)d_in[2];
    float* out = (float*)d_out;

    float* wsO = (float*)d_ws;                                   // [2048, 96]
    float* wsL = wsO + (size_t)kB * kH * kNChunk * kD;           // [2048]
    float* wsW = wsL + (size_t)kB * kH * kNChunk;                // [128, 4096]
    float* wsP = wsW + (size_t)kB * kH * kS;                     // [4096, 96]

    hipLaunchKernelGGL(attn_pass1_kernel,
                       dim3(kB * kH * kNChunk), dim3(256), 0, stream,
                       src, mask, query, wsO, wsL, wsW);
    hipLaunchKernelGGL(attn_pe_kernel,
                       dim3(kB * kH * kNSC2), dim3(128), 0, stream,
                       wsW, wsP);
    hipLaunchKernelGGL(attn_combine_kernel,
                       dim3(kB * kH), dim3(128), 0, stream,
                       wsO, wsL, wsP, out);
}